// Round 10
// baseline (3657.101 us; speedup 1.0000x reference)
//
#include <hip/hip_runtime.h>
#include <stdint.h>

// Problem dims
#define NB   64      // batch
#define NT   256     // timesteps
#define NS   512     // input feature (state)
#define NH   1024    // hidden
#define NG   4096    // 4*NH (gates)
#define NHD  512     // dense1 width
#define NA   64      // action size
#define NO   64      // n_output

typedef float f32x4  __attribute__((ext_vector_type(4)));
typedef short bf16x8 __attribute__((ext_vector_type(8)));
typedef int   i32x4  __attribute__((ext_vector_type(4)));

__device__ __forceinline__ unsigned short f2bf(float f) {
    union { float f; unsigned u; } a; a.f = f;
    unsigned u = a.u;
    return (unsigned short)((u + 0x7fffu + ((u >> 16) & 1u)) >> 16);   // RNE
}
__device__ __forceinline__ float bf2f(unsigned short h) {
    union { unsigned u; float f; } a; a.u = ((unsigned)h) << 16; return a.f;
}
__device__ __forceinline__ float sigm(float x) {
    return __fdividef(1.0f, 1.0f + __expf(-x));
}
__device__ __forceinline__ float tanh_f(float x) {
    float e = __expf(-2.0f * fabsf(x));
    float r = __fdividef(1.0f - e, 1.0f + e);
    return x >= 0.0f ? r : -r;
}
// v_perm_b32: byte-select — sel bytes 0..3 from b, 4..7 from a
__device__ __forceinline__ unsigned prm(unsigned a, unsigned b, unsigned s) {
    return __builtin_amdgcn_perm(a, b, s);
}

// sc1 load: bypasses (misses) the non-coherent per-XCD L2 -> reads the
// coherence point. Coalesced 16B/lane.
#define GLD(dst, base, off) \
    asm volatile("global_load_dwordx4 %0, %1, off offset:" #off " sc1" \
                 : "=v"(dst) : "v"(base) : "memory")
// issue order is ks-major: 4 loads per ks (2 mt x 2 halves)
#define GLD4(ks, o0, o1) \
    GLD(q[ks][0][0], hb0, o0); GLD(q[ks][0][1], hb0, o1); \
    GLD(q[ks][1][0], hb1, o0); GLD(q[ks][1][1], hb1, o1)
// normal cached load for x prefetch — anchored volatile asm so it issues
// AFTER the h burst and BEFORE the HKS waits (vmcnt numbering depends on it)
#define XLD(dst, base, off) \
    asm volatile("global_load_dwordx4 %0, %1, off offset:" #off \
                 : "=v"(dst) : "v"(base) : "memory")
// chunked wait: data-tie the chunk's regs so uses can't be hoisted above
#define WAITKS(n, ks) \
    asm volatile("s_waitcnt vmcnt(" #n ")" \
                 : "+v"(q[ks][0][0]), "+v"(q[ks][0][1]), \
                   "+v"(q[ks][1][0]), "+v"(q[ks][1][1]))

// h-phase chunk: wait for chunk ks, v_perm unpack (hi|lo<<16), 12 MFMAs.
// No #pragma inside macro bodies (r6 build failure); trip-2 loops unroll at -O3.
#define HKS(WN, ks)                                                              \
    {                                                                            \
        WAITKS(WN, ks);                                                          \
        bf16x8 fh[2], fl[2];                                                     \
        for (int mt = 0; mt < 2; ++mt) {                                         \
            i32x4 qa = q[ks][mt][0], qb = q[ks][mt][1];                          \
            i32x4 hi, lo;                                                        \
            hi[0] = (int)prm((unsigned)qa[1], (unsigned)qa[0], 0x05040100u);     \
            lo[0] = (int)prm((unsigned)qa[1], (unsigned)qa[0], 0x07060302u);     \
            hi[1] = (int)prm((unsigned)qa[3], (unsigned)qa[2], 0x05040100u);     \
            lo[1] = (int)prm((unsigned)qa[3], (unsigned)qa[2], 0x07060302u);     \
            hi[2] = (int)prm((unsigned)qb[1], (unsigned)qb[0], 0x05040100u);     \
            lo[2] = (int)prm((unsigned)qb[1], (unsigned)qb[0], 0x07060302u);     \
            hi[3] = (int)prm((unsigned)qb[3], (unsigned)qb[2], 0x05040100u);     \
            lo[3] = (int)prm((unsigned)qb[3], (unsigned)qb[2], 0x07060302u);     \
            union { i32x4 i; bf16x8 v; } ch, cl;                                 \
            ch.i = hi; cl.i = lo;                                                \
            fh[mt] = ch.v; fl[mt] = cl.v;                                        \
        }                                                                        \
        for (int mt = 0; mt < 2; ++mt)                                           \
            for (int nt = 0; nt < 2; ++nt) {                                     \
                acc[mt][nt] = __builtin_amdgcn_mfma_f32_16x16x32_bf16(fh[mt], whh[nt][ks], acc[mt][nt], 0, 0, 0); \
                acc[mt][nt] = __builtin_amdgcn_mfma_f32_16x16x32_bf16(fh[mt], whl[nt][ks], acc[mt][nt], 0, 0, 0); \
                acc[mt][nt] = __builtin_amdgcn_mfma_f32_16x16x32_bf16(fl[mt], whh[nt][ks], acc[mt][nt], 0, 0, 0); \
            }                                                                    \
    }

// Workspace layout (bytes):
//   [0)       hpack: 2 x 64 x 1024 u32 = 524288  (h as (hi|lo<<16), dbl-buffered)
//   [524288)  hF32 : 64 x 1024 f32     = 262144
//   [786432)  hid  : 64 x 512 f32      = 131072
//   [917504)  flags: 2 groups x 128 i32 = 1024
#define WS_HPK   0
#define WS_HF32  524288
#define WS_HID   786432
#define WS_FLG   917504

__global__ void prologue(unsigned int* __restrict__ hpk32,
                         unsigned int* __restrict__ flg32) {
    int idx = blockIdx.x * blockDim.x + threadIdx.x;   // 65536 threads
    hpk32[idx] = 0u;            // both parities: 131072 u32 total
    hpk32[idx + 65536] = 0u;
    if (idx < 256) flg32[idx] = 0u;
}

// Persistent LSTM recurrence, double-bf16 (hi/lo) precision.
// PLAIN launch (cooperative fails silently here — r2 post-mortem). 256 blocks
// == 256 CUs, 1 block/CU via __launch_bounds__(256,1): all co-resident.
// 2 groups x 128 blocks; group g: batches [32g,32g+32) (2 m-tiles); block bi:
// h-cols [8bi,8bi+8) x 4 gates as 2 n-tiles; wave w: K-slice. v = hi + lo
// (two bf16); tile product = 3 MFMAs (hh, hl, lh), fp32 accum.
//
// r10 = r9 with the x-prefetch asm offsets corrected (r9 post-mortem: halves
// were written at +0/+64B instead of +0/+16B -> wrong data AND reads past the
// end of x for the last batch rows -> GPU memory fault/abort). Halves of a
// lane's 8-float slice: +0 and +16 bytes; k-chunk stride 128 bytes — exactly
// the h-burst (GLD4) pattern that r8 validated.
__global__ __launch_bounds__(256, 1) void lstm_persist(
    const float* __restrict__ x, const float* __restrict__ Wx,
    const float* __restrict__ Wh, const float* __restrict__ bias,
    unsigned int* __restrict__ hpack, float* __restrict__ hF32,
    int* __restrict__ flags)
{
    const int g    = blockIdx.x >> 7;
    const int bi   = blockIdx.x & 127;
    const int tid  = threadIdx.x;
    const int w    = tid >> 6;
    const int lane = tid & 63;
    const int lm   = lane & 15;   // A: m(batch row) ; B: n ; D: col
    const int lq   = lane >> 4;   // k-quad

    __shared__ float zl[4][2][2][16][17];   // [wave][mt][nt][row][col] (+1 pad)

    // ---- one-time: weight B-fragments (hi/lo bf16) into registers ----
    // B-frag (16x16x32): lane holds B[k = lq*8 + j][n = lm], j = 0..7
    bf16x8 wxh[2][4], wxl[2][4];   // [nt][kstep] x-path, K=512/4waves
    bf16x8 whh[2][8], whl[2][8];   // [nt][kstep] h-path, K=1024/4waves
    #pragma unroll
    for (int nt = 0; nt < 2; ++nt) {
        const int gate = nt * 2 + (lm >> 3);
        const int zc   = gate * NH + bi * 8 + (lm & 7);
        #pragma unroll
        for (int ks = 0; ks < 4; ++ks)
            #pragma unroll
            for (int j = 0; j < 8; ++j) {
                int k = w * 128 + ks * 32 + lq * 8 + j;
                float v = Wx[(size_t)k * NG + zc];
                unsigned short h = f2bf(v);
                wxh[nt][ks][j] = (short)h;
                wxl[nt][ks][j] = (short)f2bf(v - bf2f(h));
            }
        #pragma unroll
        for (int ks = 0; ks < 8; ++ks)
            #pragma unroll
            for (int j = 0; j < 8; ++j) {
                int k = w * 256 + ks * 32 + lq * 8 + j;
                float v = Wh[(size_t)k * NG + zc];
                unsigned short h = f2bf(v);
                whh[nt][ks][j] = (short)h;
                whl[nt][ks][j] = (short)f2bf(v - bf2f(h));
            }
    }

    // ---- per-thread cell state: thread owns (batch, h-col) ----
    const int bloc   = tid >> 3;         // batch-in-group 0..31
    const int hcc    = tid & 7;          // h-col-in-block 0..7
    const int gbatch = g * 32 + bloc;
    const int col    = bi * 8 + hcc;
    const int emt    = bloc >> 4;        // m-tile for LDS read
    const int emr    = bloc & 15;        // row within m-tile
    float bgate[4];
    #pragma unroll
    for (int gt = 0; gt < 4; ++gt) bgate[gt] = bias[gt * NH + col];
    float c = 0.0f;

    int* const gflags = flags + g * 128;
    int* const myflag = gflags + bi;

    // x fragments raw fp32, loaded one step ahead: [mt][ks][half]
    f32x4 xr[2][4][2];
    #pragma unroll
    for (int mt = 0; mt < 2; ++mt) {
        const float* xs = x + (size_t)(g * 32 + mt * 16 + lm) * NT * NS
                            + w * 128 + lq * 8;
        #pragma unroll
        for (int ks = 0; ks < 4; ++ks) {
            const f32x4* p = reinterpret_cast<const f32x4*>(xs + ks * 32);
            xr[mt][ks][0] = p[0];
            xr[mt][ks][1] = p[1];
        }
    }

    #pragma unroll 1
    for (int t = 0; t < NT; ++t) {
        // ---- wait for h_t: EVERY wave polls all 128 group flags (2/lane).
        // vmcnt is clean here (publish-sync drained everything) so each poll
        // iteration waits only on its own flag load. ----
        {
            const unsigned long long* fp =
                reinterpret_cast<const unsigned long long*>(gflags + lane * 2);
            for (;;) {
                unsigned long long v = __hip_atomic_load(fp, __ATOMIC_RELAXED,
                                                         __HIP_MEMORY_SCOPE_AGENT);
                int f0 = (int)(v & 0xffffffffu);
                int f1 = (int)(v >> 32);
                if (__all(f0 >= t && f1 >= t)) break;
                __builtin_amdgcn_s_sleep(1);
            }
            // no fence: h loads below are sc1 (coherent past L2)
        }

        // ---- issue h sc1 load burst: 32 x dwordx4, ks-major ----
        const size_t par = (size_t)(t & 1) * (NB * NH);
        i32x4 q[8][2][2];   // [ks][mt][half]
        const unsigned int* hb0 = hpack + par + (size_t)(g * 32 + lm) * NH
                                + w * 256 + lq * 8;
        const unsigned int* hb1 = hb0 + (size_t)16 * NH;
        GLD4(0, 0, 16);    GLD4(1, 128, 144); GLD4(2, 256, 272); GLD4(3, 384, 400);
        GLD4(4, 512, 528); GLD4(5, 640, 656); GLD4(6, 768, 784); GLD4(7, 896, 912);

        // ---- x-phase in the h-load shadow: convert + 48 MFMAs (consumes xr) ----
        f32x4 acc[2][2];
        #pragma unroll
        for (int mt = 0; mt < 2; ++mt)
            #pragma unroll
            for (int nt = 0; nt < 2; ++nt) {
                acc[mt][nt][0] = 0.f; acc[mt][nt][1] = 0.f;
                acc[mt][nt][2] = 0.f; acc[mt][nt][3] = 0.f;
            }
        #pragma unroll
        for (int ks = 0; ks < 4; ++ks) {
            bf16x8 axh[2], axl[2];
            #pragma unroll
            for (int mt = 0; mt < 2; ++mt) {
                f32x4 vlo = xr[mt][ks][0], vhi = xr[mt][ks][1];
                #pragma unroll
                for (int j = 0; j < 4; ++j) {
                    unsigned short h0 = f2bf(vlo[j]);
                    axh[mt][j]     = (short)h0;
                    axl[mt][j]     = (short)f2bf(vlo[j] - bf2f(h0));
                    unsigned short h1 = f2bf(vhi[j]);
                    axh[mt][4 + j] = (short)h1;
                    axl[mt][4 + j] = (short)f2bf(vhi[j] - bf2f(h1));
                }
            }
            #pragma unroll
            for (int mt = 0; mt < 2; ++mt)
                #pragma unroll
                for (int nt = 0; nt < 2; ++nt) {
                    acc[mt][nt] = __builtin_amdgcn_mfma_f32_16x16x32_bf16(axh[mt], wxh[nt][ks], acc[mt][nt], 0, 0, 0);
                    acc[mt][nt] = __builtin_amdgcn_mfma_f32_16x16x32_bf16(axh[mt], wxl[nt][ks], acc[mt][nt], 0, 0, 0);
                    acc[mt][nt] = __builtin_amdgcn_mfma_f32_16x16x32_bf16(axl[mt], wxh[nt][ks], acc[mt][nt], 0, 0, 0);
                }
        }

        // ---- x-prefetch for t+1 (anchored asm, AFTER h burst, BEFORE h-phase;
        // WAR on xr keeps it after the x-phase reads; drains at publish-sync).
        // Unconditional (t+1 wraps on last iter, data unused) so outstanding
        // count at the HKS waits is always exactly 48.
        // Offsets: halves at +0/+16 B, k-chunk stride 128 B (r9 bug: +0/+64). ----
        {
            const int tn = (t + 1) & (NT - 1);
            const float* xb0 = x + ((size_t)(g * 32 + lm) * NT + tn) * NS
                                 + w * 128 + lq * 8;
            const float* xb1 = xb0 + (size_t)16 * NT * NS;
            XLD(xr[0][0][0], xb0, 0);   XLD(xr[0][0][1], xb0, 16);
            XLD(xr[0][1][0], xb0, 128); XLD(xr[0][1][1], xb0, 144);
            XLD(xr[0][2][0], xb0, 256); XLD(xr[0][2][1], xb0, 272);
            XLD(xr[0][3][0], xb0, 384); XLD(xr[0][3][1], xb0, 400);
            XLD(xr[1][0][0], xb1, 0);   XLD(xr[1][0][1], xb1, 16);
            XLD(xr[1][1][0], xb1, 128); XLD(xr[1][1][1], xb1, 144);
            XLD(xr[1][2][0], xb1, 256); XLD(xr[1][2][1], xb1, 272);
            XLD(xr[1][3][0], xb1, 384); XLD(xr[1][3][1], xb1, 400);
        }

        // ---- h-phase: chunked waits (48 outstanding: 32 h + 16 x), unpack,
        // 3-term MFMAs. Chunk k done when <= 44-4k outstanding. ----
        HKS(44, 0) HKS(40, 1) HKS(36, 2) HKS(32, 3)
        HKS(28, 4) HKS(24, 5) HKS(20, 6) HKS(16, 7)

        // ---- cross-wave K-reduction via LDS (D: row = lq*4+r, col = lm) ----
        #pragma unroll
        for (int mt = 0; mt < 2; ++mt)
            #pragma unroll
            for (int nt = 0; nt < 2; ++nt)
                #pragma unroll
                for (int r = 0; r < 4; ++r)
                    zl[w][mt][nt][lq * 4 + r][lm] = acc[mt][nt][r];
        __syncthreads();

        float zg[4];
        #pragma unroll
        for (int gt = 0; gt < 4; ++gt) {
            const int nt = gt >> 1;
            const int n  = (gt & 1) * 8 + hcc;
            zg[gt] = zl[0][emt][nt][emr][n] + zl[1][emt][nt][emr][n]
                   + zl[2][emt][nt][emr][n] + zl[3][emt][nt][emr][n] + bgate[gt];
        }

        // Keras gate order: i, f, g, o
        float ig = sigm(zg[0]);
        float fg = sigm(zg[1]);
        float gg = tanh_f(zg[2]);
        float og = sigm(zg[3]);
        c = fg * c + ig * gg;
        float hv = og * tanh_f(c);

        unsigned short hb = f2bf(hv);
        unsigned short lb = f2bf(hv - bf2f(hb));
        unsigned pk = (unsigned)hb | ((unsigned)lb << 16);
        const size_t po = (size_t)((t + 1) & 1) * (NB * NH) + (size_t)gbatch * NH + col;
        __hip_atomic_store(hpack + po, pk, __ATOMIC_RELAXED, __HIP_MEMORY_SCOPE_AGENT);
        if (t == NT - 1) hF32[(size_t)gbatch * NH + col] = hv;

        // ---- publish: __syncthreads drains every wave's vmcnt (h stores at
        // coherence point + x prefetch), then relaxed flag store — no fences ----
        __syncthreads();
        if (tid == 0)
            __hip_atomic_store(myflag, t + 1, __ATOMIC_RELAXED, __HIP_MEMORY_SCOPE_AGENT);
    }
}

// hid = relu(hF32 @ Wd1 + bd1)   [64,1024]x[1024,512]
__global__ void head1(const float* __restrict__ hF32, const float* __restrict__ Wd1,
                      const float* __restrict__ bd1, float* __restrict__ hid)
{
    int b = blockIdx.x >> 1;
    int n = (blockIdx.x & 1) * 256 + threadIdx.x;
    const float* hrow = hF32 + (size_t)b * NH;
    float acc = bd1[n];
    #pragma unroll 4
    for (int k = 0; k < NH; ++k)
        acc += hrow[k] * Wd1[(size_t)k * NHD + n];
    hid[(size_t)b * NHD + n] = fmaxf(acc, 0.0f);
}

// out = [hid | actions | horizon] @ Wd2 + bd2   K = 512 + 64 + 1 = 577
__global__ void head2(const float* __restrict__ hid, const float* __restrict__ act,
                      const float* __restrict__ hor, const float* __restrict__ Wd2,
                      const float* __restrict__ bd2, float* __restrict__ out)
{
    int b = blockIdx.x;
    int n = threadIdx.x;
    float acc = bd2[n];
    const float* hrow = hid + (size_t)b * NHD;
    #pragma unroll 4
    for (int k = 0; k < NHD; ++k) acc += hrow[k] * Wd2[(size_t)k * NO + n];
    const float* arow = act + (size_t)b * NA;
    #pragma unroll
    for (int k = 0; k < NA; ++k) acc += arow[k] * Wd2[(size_t)(NHD + k) * NO + n];
    acc += hor[b] * Wd2[(size_t)576 * NO + n];
    out[(size_t)b * NO + n] = acc;
}

extern "C" void kernel_launch(void* const* d_in, const int* in_sizes, int n_in,
                              void* d_out, int out_size, void* d_ws, size_t ws_size,
                              hipStream_t stream)
{
    (void)in_sizes; (void)n_in; (void)out_size; (void)ws_size;
    const float* x    = (const float*)d_in[0];
    const float* act  = (const float*)d_in[1];
    const float* hor  = (const float*)d_in[2];
    const float* Wx   = (const float*)d_in[3];
    const float* Wh   = (const float*)d_in[4];
    const float* bias = (const float*)d_in[5];
    const float* Wd1  = (const float*)d_in[6];
    const float* bd1  = (const float*)d_in[7];
    const float* Wd2  = (const float*)d_in[8];
    const float* bd2  = (const float*)d_in[9];
    float* out = (float*)d_out;

    char* wsb = (char*)d_ws;
    unsigned int* hpk = (unsigned int*)(wsb + WS_HPK);
    float* hF32 = (float*)(wsb + WS_HF32);
    float* hid  = (float*)(wsb + WS_HID);
    int*   flg  = (int*)(wsb + WS_FLG);

    prologue<<<256, 256, 0, stream>>>(hpk, (unsigned int*)(wsb + WS_FLG));

    // Plain launch (NOT cooperative — see r2 post-mortem). 256 blocks == 256 CUs.
    lstm_persist<<<dim3(256), dim3(256), 0, stream>>>(x, Wx, Wh, bias,
                                                      hpk, hF32, flg);

    head1<<<128, 256, 0, stream>>>(hF32, Wd1, bd1, hid);
    head2<<<64, 64, 0, stream>>>(hid, act, hor, Wd2, bd2, out);
}

// Round 11
// 3147.491 us; speedup vs baseline: 1.1619x; 1.1619x over previous
//
#include <hip/hip_runtime.h>
#include <stdint.h>

// Problem dims
#define NB   64      // batch
#define NT   256     // timesteps
#define NS   512     // input feature (state)
#define NH   1024    // hidden
#define NG   4096    // 4*NH (gates)
#define NHD  512     // dense1 width
#define NA   64      // action size
#define NO   64      // n_output

typedef float f32x4  __attribute__((ext_vector_type(4)));
typedef short bf16x8 __attribute__((ext_vector_type(8)));
typedef int   i32x4  __attribute__((ext_vector_type(4)));

__device__ __forceinline__ unsigned short f2bf(float f) {
    union { float f; unsigned u; } a; a.f = f;
    unsigned u = a.u;
    return (unsigned short)((u + 0x7fffu + ((u >> 16) & 1u)) >> 16);   // RNE
}
__device__ __forceinline__ float bf2f(unsigned short h) {
    union { unsigned u; float f; } a; a.u = ((unsigned)h) << 16; return a.f;
}
__device__ __forceinline__ float sigm(float x) {
    return __fdividef(1.0f, 1.0f + __expf(-x));
}
__device__ __forceinline__ float tanh_f(float x) {
    float e = __expf(-2.0f * fabsf(x));
    float r = __fdividef(1.0f - e, 1.0f + e);
    return x >= 0.0f ? r : -r;
}
// v_perm_b32: byte-select — sel bytes 0..3 from b, 4..7 from a
__device__ __forceinline__ unsigned prm(unsigned a, unsigned b, unsigned s) {
    return __builtin_amdgcn_perm(a, b, s);
}

// sc1 load: bypasses (misses) the non-coherent per-XCD L2 -> reads the
// coherence point. Coalesced 16B/lane.
#define GLD(dst, base, off) \
    asm volatile("global_load_dwordx4 %0, %1, off offset:" #off " sc1" \
                 : "=v"(dst) : "v"(base) : "memory")
// issue order is ks-major: 4 loads per ks (2 mt x 2 halves)
#define GLD4(ks, o0, o1) \
    GLD(q[ks][0][0], hb0, o0); GLD(q[ks][0][1], hb0, o1); \
    GLD(q[ks][1][0], hb1, o0); GLD(q[ks][1][1], hb1, o1)
// normal cached load for x prefetch — anchored volatile asm so it issues
// AFTER the h burst and BEFORE the HKS waits (vmcnt numbering depends on it)
#define XLD(dst, base, off) \
    asm volatile("global_load_dwordx4 %0, %1, off offset:" #off \
                 : "=v"(dst) : "v"(base) : "memory")
// chunked wait: data-tie the chunk's regs so uses can't be hoisted above
#define WAITKS(n, ks) \
    asm volatile("s_waitcnt vmcnt(" #n ")" \
                 : "+v"(q[ks][0][0]), "+v"(q[ks][0][1]), \
                   "+v"(q[ks][1][0]), "+v"(q[ks][1][1]))

// h-phase chunk: wait for chunk ks, v_perm unpack (hi|lo<<16), 12 MFMAs.
// No #pragma inside macro bodies (r6 build failure); trip-2 loops unroll at -O3.
#define HKS(WN, ks)                                                              \
    {                                                                            \
        WAITKS(WN, ks);                                                          \
        bf16x8 fh[2], fl[2];                                                     \
        for (int mt = 0; mt < 2; ++mt) {                                         \
            i32x4 qa = q[ks][mt][0], qb = q[ks][mt][1];                          \
            i32x4 hi, lo;                                                        \
            hi[0] = (int)prm((unsigned)qa[1], (unsigned)qa[0], 0x05040100u);     \
            lo[0] = (int)prm((unsigned)qa[1], (unsigned)qa[0], 0x07060302u);     \
            hi[1] = (int)prm((unsigned)qa[3], (unsigned)qa[2], 0x05040100u);     \
            lo[1] = (int)prm((unsigned)qa[3], (unsigned)qa[2], 0x07060302u);     \
            hi[2] = (int)prm((unsigned)qb[1], (unsigned)qb[0], 0x05040100u);     \
            lo[2] = (int)prm((unsigned)qb[1], (unsigned)qb[0], 0x07060302u);     \
            hi[3] = (int)prm((unsigned)qb[3], (unsigned)qb[2], 0x05040100u);     \
            lo[3] = (int)prm((unsigned)qb[3], (unsigned)qb[2], 0x07060302u);     \
            union { i32x4 i; bf16x8 v; } ch, cl;                                 \
            ch.i = hi; cl.i = lo;                                                \
            fh[mt] = ch.v; fl[mt] = cl.v;                                        \
        }                                                                        \
        for (int mt = 0; mt < 2; ++mt)                                           \
            for (int nt = 0; nt < 2; ++nt) {                                     \
                acc[mt][nt] = __builtin_amdgcn_mfma_f32_16x16x32_bf16(fh[mt], whh[nt][ks], acc[mt][nt], 0, 0, 0); \
                acc[mt][nt] = __builtin_amdgcn_mfma_f32_16x16x32_bf16(fh[mt], whl[nt][ks], acc[mt][nt], 0, 0, 0); \
                acc[mt][nt] = __builtin_amdgcn_mfma_f32_16x16x32_bf16(fl[mt], whh[nt][ks], acc[mt][nt], 0, 0, 0); \
            }                                                                    \
    }

// Workspace layout (bytes):
//   [0)       hpack: 2 x 64 x 1024 u32 = 524288  (h as (hi|lo<<16), dbl-buffered)
//   [524288)  hF32 : 64 x 1024 f32     = 262144
//   [786432)  hid  : 64 x 512 f32      = 131072
//   [917504)  flags: 2 groups x 128 i32 = 1024
#define WS_HPK   0
#define WS_HF32  524288
#define WS_HID   786432
#define WS_FLG   917504

__global__ void prologue(unsigned int* __restrict__ hpk32,
                         unsigned int* __restrict__ flg32) {
    int idx = blockIdx.x * blockDim.x + threadIdx.x;   // 65536 threads
    hpk32[idx] = 0u;            // both parities: 131072 u32 total
    hpk32[idx + 65536] = 0u;
    if (idx < 256) flg32[idx] = 0u;
}

// Persistent LSTM recurrence, double-bf16 (hi/lo) precision.
// PLAIN launch (cooperative fails silently here — r2 post-mortem). 256 blocks
// == 256 CUs, 1 block/CU via __launch_bounds__(256,1): all co-resident.
// 2 groups x 128 blocks; group g: batches [32g,32g+32) (2 m-tiles); block bi:
// h-cols [8bi,8bi+8) x 4 gates as 2 n-tiles; wave w: K-slice. v = hi + lo
// (two bf16); tile product = 3 MFMAs (hh, hl, lh), fp32 accum.
//
// r11 = r8 poll structure (wave0-only poll + syncthreads release — r10's
// all-wave polling quadrupled agent-scope flag traffic onto the same
// coherence-point slice the sc1 h-exchange uses: 2397 -> 3657us regression)
// + r10's corrected x-prefetch placement/offsets + v_perm unpack + chunked
// HKS waits (48-outstanding numbering).
__global__ __launch_bounds__(256, 1) void lstm_persist(
    const float* __restrict__ x, const float* __restrict__ Wx,
    const float* __restrict__ Wh, const float* __restrict__ bias,
    unsigned int* __restrict__ hpack, float* __restrict__ hF32,
    int* __restrict__ flags)
{
    const int g    = blockIdx.x >> 7;
    const int bi   = blockIdx.x & 127;
    const int tid  = threadIdx.x;
    const int w    = tid >> 6;
    const int lane = tid & 63;
    const int lm   = lane & 15;   // A: m(batch row) ; B: n ; D: col
    const int lq   = lane >> 4;   // k-quad

    __shared__ float zl[4][2][2][16][17];   // [wave][mt][nt][row][col] (+1 pad)

    // ---- one-time: weight B-fragments (hi/lo bf16) into registers ----
    // B-frag (16x16x32): lane holds B[k = lq*8 + j][n = lm], j = 0..7
    bf16x8 wxh[2][4], wxl[2][4];   // [nt][kstep] x-path, K=512/4waves
    bf16x8 whh[2][8], whl[2][8];   // [nt][kstep] h-path, K=1024/4waves
    #pragma unroll
    for (int nt = 0; nt < 2; ++nt) {
        const int gate = nt * 2 + (lm >> 3);
        const int zc   = gate * NH + bi * 8 + (lm & 7);
        #pragma unroll
        for (int ks = 0; ks < 4; ++ks)
            #pragma unroll
            for (int j = 0; j < 8; ++j) {
                int k = w * 128 + ks * 32 + lq * 8 + j;
                float v = Wx[(size_t)k * NG + zc];
                unsigned short h = f2bf(v);
                wxh[nt][ks][j] = (short)h;
                wxl[nt][ks][j] = (short)f2bf(v - bf2f(h));
            }
        #pragma unroll
        for (int ks = 0; ks < 8; ++ks)
            #pragma unroll
            for (int j = 0; j < 8; ++j) {
                int k = w * 256 + ks * 32 + lq * 8 + j;
                float v = Wh[(size_t)k * NG + zc];
                unsigned short h = f2bf(v);
                whh[nt][ks][j] = (short)h;
                whl[nt][ks][j] = (short)f2bf(v - bf2f(h));
            }
    }

    // ---- per-thread cell state: thread owns (batch, h-col) ----
    const int bloc   = tid >> 3;         // batch-in-group 0..31
    const int hcc    = tid & 7;          // h-col-in-block 0..7
    const int gbatch = g * 32 + bloc;
    const int col    = bi * 8 + hcc;
    const int emt    = bloc >> 4;        // m-tile for LDS read
    const int emr    = bloc & 15;        // row within m-tile
    float bgate[4];
    #pragma unroll
    for (int gt = 0; gt < 4; ++gt) bgate[gt] = bias[gt * NH + col];
    float c = 0.0f;

    int* const gflags = flags + g * 128;
    int* const myflag = gflags + bi;

    // x fragments raw fp32, loaded one step ahead: [mt][ks][half]
    f32x4 xr[2][4][2];
    #pragma unroll
    for (int mt = 0; mt < 2; ++mt) {
        const float* xs = x + (size_t)(g * 32 + mt * 16 + lm) * NT * NS
                            + w * 128 + lq * 8;
        #pragma unroll
        for (int ks = 0; ks < 4; ++ks) {
            const f32x4* p = reinterpret_cast<const f32x4*>(xs + ks * 32);
            xr[mt][ks][0] = p[0];
            xr[mt][ks][1] = p[1];
        }
    }

    #pragma unroll 1
    for (int t = 0; t < NT; ++t) {
        // ---- wait for h_t: ONLY wave0 polls (256 pollers device-wide, not
        // 1024 — r10's all-wave polling saturated the coherence-point slice);
        // syncthreads releases waves 1-3. ----
        if (w == 0) {
            const unsigned long long* fp =
                reinterpret_cast<const unsigned long long*>(gflags + lane * 2);
            for (;;) {
                unsigned long long v = __hip_atomic_load(fp, __ATOMIC_RELAXED,
                                                         __HIP_MEMORY_SCOPE_AGENT);
                int f0 = (int)(v & 0xffffffffu);
                int f1 = (int)(v >> 32);
                if (__all(f0 >= t && f1 >= t)) break;
                __builtin_amdgcn_s_sleep(1);
            }
            // no fence: h loads below are sc1 (coherent past L2)
        }
        __syncthreads();

        // ---- issue h sc1 load burst: 32 x dwordx4, ks-major ----
        const size_t par = (size_t)(t & 1) * (NB * NH);
        i32x4 q[8][2][2];   // [ks][mt][half]
        const unsigned int* hb0 = hpack + par + (size_t)(g * 32 + lm) * NH
                                + w * 256 + lq * 8;
        const unsigned int* hb1 = hb0 + (size_t)16 * NH;
        GLD4(0, 0, 16);    GLD4(1, 128, 144); GLD4(2, 256, 272); GLD4(3, 384, 400);
        GLD4(4, 512, 528); GLD4(5, 640, 656); GLD4(6, 768, 784); GLD4(7, 896, 912);

        // ---- x-phase in the h-load shadow: convert + 48 MFMAs (consumes xr) ----
        f32x4 acc[2][2];
        #pragma unroll
        for (int mt = 0; mt < 2; ++mt)
            #pragma unroll
            for (int nt = 0; nt < 2; ++nt) {
                acc[mt][nt][0] = 0.f; acc[mt][nt][1] = 0.f;
                acc[mt][nt][2] = 0.f; acc[mt][nt][3] = 0.f;
            }
        #pragma unroll
        for (int ks = 0; ks < 4; ++ks) {
            bf16x8 axh[2], axl[2];
            #pragma unroll
            for (int mt = 0; mt < 2; ++mt) {
                f32x4 vlo = xr[mt][ks][0], vhi = xr[mt][ks][1];
                #pragma unroll
                for (int j = 0; j < 4; ++j) {
                    unsigned short h0 = f2bf(vlo[j]);
                    axh[mt][j]     = (short)h0;
                    axl[mt][j]     = (short)f2bf(vlo[j] - bf2f(h0));
                    unsigned short h1 = f2bf(vhi[j]);
                    axh[mt][4 + j] = (short)h1;
                    axl[mt][4 + j] = (short)f2bf(vhi[j] - bf2f(h1));
                }
            }
            #pragma unroll
            for (int mt = 0; mt < 2; ++mt)
                #pragma unroll
                for (int nt = 0; nt < 2; ++nt) {
                    acc[mt][nt] = __builtin_amdgcn_mfma_f32_16x16x32_bf16(axh[mt], wxh[nt][ks], acc[mt][nt], 0, 0, 0);
                    acc[mt][nt] = __builtin_amdgcn_mfma_f32_16x16x32_bf16(axh[mt], wxl[nt][ks], acc[mt][nt], 0, 0, 0);
                    acc[mt][nt] = __builtin_amdgcn_mfma_f32_16x16x32_bf16(axl[mt], wxh[nt][ks], acc[mt][nt], 0, 0, 0);
                }
        }

        // ---- x-prefetch for t+1 (anchored asm, AFTER h burst, BEFORE h-phase;
        // WAR on xr keeps it after the x-phase reads; drains at publish-sync;
        // never gates the poll). Unconditional (t+1 wraps on last iter, data
        // unused) so outstanding count at the HKS waits is always exactly 48.
        // Offsets: halves at +0/+16 B, k-chunk stride 128 B. ----
        {
            const int tn = (t + 1) & (NT - 1);
            const float* xb0 = x + ((size_t)(g * 32 + lm) * NT + tn) * NS
                                 + w * 128 + lq * 8;
            const float* xb1 = xb0 + (size_t)16 * NT * NS;
            XLD(xr[0][0][0], xb0, 0);   XLD(xr[0][0][1], xb0, 16);
            XLD(xr[0][1][0], xb0, 128); XLD(xr[0][1][1], xb0, 144);
            XLD(xr[0][2][0], xb0, 256); XLD(xr[0][2][1], xb0, 272);
            XLD(xr[0][3][0], xb0, 384); XLD(xr[0][3][1], xb0, 400);
            XLD(xr[1][0][0], xb1, 0);   XLD(xr[1][0][1], xb1, 16);
            XLD(xr[1][1][0], xb1, 128); XLD(xr[1][1][1], xb1, 144);
            XLD(xr[1][2][0], xb1, 256); XLD(xr[1][2][1], xb1, 272);
            XLD(xr[1][3][0], xb1, 384); XLD(xr[1][3][1], xb1, 400);
        }

        // ---- h-phase: chunked waits (48 outstanding: 32 h + 16 x), unpack,
        // 3-term MFMAs. Chunk k done when <= 44-4k outstanding. ----
        HKS(44, 0) HKS(40, 1) HKS(36, 2) HKS(32, 3)
        HKS(28, 4) HKS(24, 5) HKS(20, 6) HKS(16, 7)

        // ---- cross-wave K-reduction via LDS (D: row = lq*4+r, col = lm) ----
        #pragma unroll
        for (int mt = 0; mt < 2; ++mt)
            #pragma unroll
            for (int nt = 0; nt < 2; ++nt)
                #pragma unroll
                for (int r = 0; r < 4; ++r)
                    zl[w][mt][nt][lq * 4 + r][lm] = acc[mt][nt][r];
        __syncthreads();

        float zg[4];
        #pragma unroll
        for (int gt = 0; gt < 4; ++gt) {
            const int nt = gt >> 1;
            const int n  = (gt & 1) * 8 + hcc;
            zg[gt] = zl[0][emt][nt][emr][n] + zl[1][emt][nt][emr][n]
                   + zl[2][emt][nt][emr][n] + zl[3][emt][nt][emr][n] + bgate[gt];
        }

        // Keras gate order: i, f, g, o
        float ig = sigm(zg[0]);
        float fg = sigm(zg[1]);
        float gg = tanh_f(zg[2]);
        float og = sigm(zg[3]);
        c = fg * c + ig * gg;
        float hv = og * tanh_f(c);

        unsigned short hb = f2bf(hv);
        unsigned short lb = f2bf(hv - bf2f(hb));
        unsigned pk = (unsigned)hb | ((unsigned)lb << 16);
        const size_t po = (size_t)((t + 1) & 1) * (NB * NH) + (size_t)gbatch * NH + col;
        __hip_atomic_store(hpack + po, pk, __ATOMIC_RELAXED, __HIP_MEMORY_SCOPE_AGENT);
        if (t == NT - 1) hF32[(size_t)gbatch * NH + col] = hv;

        // ---- publish: __syncthreads drains every wave's vmcnt (h stores at
        // coherence point + x prefetch), then relaxed flag store — no fences ----
        __syncthreads();
        if (tid == 0)
            __hip_atomic_store(myflag, t + 1, __ATOMIC_RELAXED, __HIP_MEMORY_SCOPE_AGENT);
    }
}

// hid = relu(hF32 @ Wd1 + bd1)   [64,1024]x[1024,512]
__global__ void head1(const float* __restrict__ hF32, const float* __restrict__ Wd1,
                      const float* __restrict__ bd1, float* __restrict__ hid)
{
    int b = blockIdx.x >> 1;
    int n = (blockIdx.x & 1) * 256 + threadIdx.x;
    const float* hrow = hF32 + (size_t)b * NH;
    float acc = bd1[n];
    #pragma unroll 4
    for (int k = 0; k < NH; ++k)
        acc += hrow[k] * Wd1[(size_t)k * NHD + n];
    hid[(size_t)b * NHD + n] = fmaxf(acc, 0.0f);
}

// out = [hid | actions | horizon] @ Wd2 + bd2   K = 512 + 64 + 1 = 577
__global__ void head2(const float* __restrict__ hid, const float* __restrict__ act,
                      const float* __restrict__ hor, const float* __restrict__ Wd2,
                      const float* __restrict__ bd2, float* __restrict__ out)
{
    int b = blockIdx.x;
    int n = threadIdx.x;
    float acc = bd2[n];
    const float* hrow = hid + (size_t)b * NHD;
    #pragma unroll 4
    for (int k = 0; k < NHD; ++k) acc += hrow[k] * Wd2[(size_t)k * NO + n];
    const float* arow = act + (size_t)b * NA;
    #pragma unroll
    for (int k = 0; k < NA; ++k) acc += arow[k] * Wd2[(size_t)(NHD + k) * NO + n];
    acc += hor[b] * Wd2[(size_t)576 * NO + n];
    out[(size_t)b * NO + n] = acc;
}

extern "C" void kernel_launch(void* const* d_in, const int* in_sizes, int n_in,
                              void* d_out, int out_size, void* d_ws, size_t ws_size,
                              hipStream_t stream)
{
    (void)in_sizes; (void)n_in; (void)out_size; (void)ws_size;
    const float* x    = (const float*)d_in[0];
    const float* act  = (const float*)d_in[1];
    const float* hor  = (const float*)d_in[2];
    const float* Wx   = (const float*)d_in[3];
    const float* Wh   = (const float*)d_in[4];
    const float* bias = (const float*)d_in[5];
    const float* Wd1  = (const float*)d_in[6];
    const float* bd1  = (const float*)d_in[7];
    const float* Wd2  = (const float*)d_in[8];
    const float* bd2  = (const float*)d_in[9];
    float* out = (float*)d_out;

    char* wsb = (char*)d_ws;
    unsigned int* hpk = (unsigned int*)(wsb + WS_HPK);
    float* hF32 = (float*)(wsb + WS_HF32);
    float* hid  = (float*)(wsb + WS_HID);
    int*   flg  = (int*)(wsb + WS_FLG);

    prologue<<<256, 256, 0, stream>>>(hpk, (unsigned int*)(wsb + WS_FLG));

    // Plain launch (NOT cooperative — see r2 post-mortem). 256 blocks == 256 CUs.
    lstm_persist<<<dim3(256), dim3(256), 0, stream>>>(x, Wx, Wh, bias,
                                                      hpk, hF32, flg);

    head1<<<128, 256, 0, stream>>>(hF32, Wd1, bd1, hid);
    head2<<<64, 64, 0, stream>>>(hid, act, hor, Wd2, bd2, out);
}

// Round 12
// 1886.724 us; speedup vs baseline: 1.9383x; 1.6682x over previous
//
#include <hip/hip_runtime.h>
#include <stdint.h>

// Problem dims
#define NB   64      // batch
#define NT   256     // timesteps
#define NS   512     // input feature (state)
#define NH   1024    // hidden
#define NG   4096    // 4*NH (gates)
#define NHD  512     // dense1 width
#define NA   64      // action size
#define NO   64      // n_output

typedef float f32x4  __attribute__((ext_vector_type(4)));
typedef short bf16x8 __attribute__((ext_vector_type(8)));
typedef int   i32x4  __attribute__((ext_vector_type(4)));

__device__ __forceinline__ unsigned short f2bf(float f) {
    union { float f; unsigned u; } a; a.f = f;
    unsigned u = a.u;
    return (unsigned short)((u + 0x7fffu + ((u >> 16) & 1u)) >> 16);   // RNE
}
__device__ __forceinline__ float bf2f(unsigned short h) {
    union { unsigned u; float f; } a; a.u = ((unsigned)h) << 16; return a.f;
}
__device__ __forceinline__ float sigm(float x) {
    return __fdividef(1.0f, 1.0f + __expf(-x));
}
__device__ __forceinline__ float tanh_f(float x) {
    float e = __expf(-2.0f * fabsf(x));
    float r = __fdividef(1.0f - e, 1.0f + e);
    return x >= 0.0f ? r : -r;
}

// sc1 load: bypasses the non-coherent per-XCD L2 -> reads the coherence point.
#define GLD(dst, base, off) \
    asm volatile("global_load_dwordx4 %0, %1, off offset:" #off " sc1" \
                 : "=v"(dst) : "v"(base) : "memory")
// one dwordx4 (8 bf16) per mt per ks
#define GLD2(ks, off) \
    GLD(q[ks][0], hb0, off); GLD(q[ks][1], hb1, off)

// h-phase chunk: wait for chunk ks (16 h loads outstanding at phase start;
// chunk ks retired when vmcnt <= 14-2ks), then 8 MFMAs (h is bf16-only:
// terms hh and hl; the lh term is gone). No #pragma in macro bodies (r6).
#define HKS(WN, ks)                                                              \
    {                                                                            \
        asm volatile("s_waitcnt vmcnt(" #WN ")"                                  \
                     : "+v"(q[ks][0]), "+v"(q[ks][1]));                          \
        union { i32x4 i; bf16x8 v; } u0, u1;                                     \
        u0.i = q[ks][0]; u1.i = q[ks][1];                                        \
        bf16x8 fh[2]; fh[0] = u0.v; fh[1] = u1.v;                                \
        for (int mt = 0; mt < 2; ++mt)                                           \
            for (int nt = 0; nt < 2; ++nt) {                                     \
                acc[mt][nt] = __builtin_amdgcn_mfma_f32_16x16x32_bf16(fh[mt], whh[nt][ks], acc[mt][nt], 0, 0, 0); \
                acc[mt][nt] = __builtin_amdgcn_mfma_f32_16x16x32_bf16(fh[mt], whl[nt][ks], acc[mt][nt], 0, 0, 0); \
            }                                                                    \
    }

// Workspace layout (bytes):
//   [0)       hpk : 2 x 64 x 1024 bf16 = 262144  (h bf16-only, dbl-buffered)
//   [262144)  hF32: 64 x 1024 f32      = 262144
//   [524288)  hid : 64 x 512 f32       = 131072
//   [655360)  flags: 2 groups x 128 i32 = 1024
#define WS_HPK   0
#define WS_HF32  262144
#define WS_HID   524288
#define WS_FLG   655360

__global__ void prologue(unsigned int* __restrict__ hpk32,
                         unsigned int* __restrict__ flg32) {
    int idx = blockIdx.x * blockDim.x + threadIdx.x;   // 65536 threads
    hpk32[idx] = 0u;            // 65536 u32 = 131072 bf16 = both parities
    if (idx < 256) flg32[idx] = 0u;
}

// Persistent LSTM recurrence. Weights & x: double-bf16 hi/lo (exact);
// h exchange: bf16-ONLY (r12 — halves the sc1 broadcast from 32 to 16
// MB/step, which r8's arithmetic shows is the binding constraint).
// PLAIN launch (cooperative fails silently — r2). 256 blocks == 256 CUs,
// 1 block/CU. 2 groups x 128 blocks; group g: batches [32g,32g+32)
// (2 m-tiles); block bi: h-cols [8bi,8bi+8) x 4 gates as 2 n-tiles;
// wave w: K-slice.
//
// Structure = EXACT r8 skeleton (fastest measured): wave0-only poll +
// syncthreads release; x-prefetch as C++ loads AFTER the flag publish
// (flies during the spin window — r11 showed mid-step placement costs
// ~2.7us/step); h sc1 burst post-poll; x-phase in the h-load shadow;
// chunked vmcnt h-phase.
// Epilogue: threads 0..127 own TWO adjacent h-cols (h store must be a
// 4-byte agent atomic; 2-byte atomics don't exist).
__global__ __launch_bounds__(256, 1) void lstm_persist(
    const float* __restrict__ x, const float* __restrict__ Wx,
    const float* __restrict__ Wh, const float* __restrict__ bias,
    unsigned short* __restrict__ hpack, float* __restrict__ hF32,
    int* __restrict__ flags)
{
    const int g    = blockIdx.x >> 7;
    const int bi   = blockIdx.x & 127;
    const int tid  = threadIdx.x;
    const int w    = tid >> 6;
    const int lane = tid & 63;
    const int lm   = lane & 15;   // A: m(batch row) ; B: n ; D: col
    const int lq   = lane >> 4;   // k-quad

    __shared__ float zl[4][2][2][16][17];   // [wave][mt][nt][row][col] (+1 pad)

    // ---- one-time: weight B-fragments (hi/lo bf16) into registers ----
    // B-frag (16x16x32): lane holds B[k = lq*8 + j][n = lm], j = 0..7
    bf16x8 wxh[2][4], wxl[2][4];   // [nt][kstep] x-path, K=512/4waves
    bf16x8 whh[2][8], whl[2][8];   // [nt][kstep] h-path, K=1024/4waves
    #pragma unroll
    for (int nt = 0; nt < 2; ++nt) {
        const int gate = nt * 2 + (lm >> 3);
        const int zc   = gate * NH + bi * 8 + (lm & 7);
        #pragma unroll
        for (int ks = 0; ks < 4; ++ks)
            #pragma unroll
            for (int j = 0; j < 8; ++j) {
                int k = w * 128 + ks * 32 + lq * 8 + j;
                float v = Wx[(size_t)k * NG + zc];
                unsigned short h = f2bf(v);
                wxh[nt][ks][j] = (short)h;
                wxl[nt][ks][j] = (short)f2bf(v - bf2f(h));
            }
        #pragma unroll
        for (int ks = 0; ks < 8; ++ks)
            #pragma unroll
            for (int j = 0; j < 8; ++j) {
                int k = w * 256 + ks * 32 + lq * 8 + j;
                float v = Wh[(size_t)k * NG + zc];
                unsigned short h = f2bf(v);
                whh[nt][ks][j] = (short)h;
                whl[nt][ks][j] = (short)f2bf(v - bf2f(h));
            }
    }

    // ---- per-thread epilogue state: threads 0..127 own 2 cells each ----
    const int et     = tid & 127;
    const int bloc   = et >> 2;          // batch-in-group 0..31
    const int prc    = et & 3;           // col-pair 0..3 (block owns 8 cols)
    const int gbatch = g * 32 + bloc;
    const int colp   = bi * 8 + prc * 2; // first col of the pair
    const int emt    = bloc >> 4;        // m-tile for LDS read
    const int emr    = bloc & 15;        // row within m-tile
    float bgate[2][4];
    #pragma unroll
    for (int j = 0; j < 2; ++j)
        #pragma unroll
        for (int gt = 0; gt < 4; ++gt)
            bgate[j][gt] = bias[gt * NH + colp + j];
    float c2[2] = {0.0f, 0.0f};

    int* const gflags = flags + g * 128;
    int* const myflag = gflags + bi;
    unsigned int* const hpk32 = reinterpret_cast<unsigned int*>(hpack);

    // x fragments raw fp32, loaded one step ahead: [mt][ks][half]
    f32x4 xr[2][4][2];
    #pragma unroll
    for (int mt = 0; mt < 2; ++mt) {
        const float* xs = x + (size_t)(g * 32 + mt * 16 + lm) * NT * NS
                            + w * 128 + lq * 8;
        #pragma unroll
        for (int ks = 0; ks < 4; ++ks) {
            const f32x4* p = reinterpret_cast<const f32x4*>(xs + ks * 32);
            xr[mt][ks][0] = p[0];
            xr[mt][ks][1] = p[1];
        }
    }

    #pragma unroll 1
    for (int t = 0; t < NT; ++t) {
        // ---- wait for h_t: ONLY wave0 polls (256 pollers device-wide;
        // all-wave polling saturates the coherence path — r10). The poll's
        // own waits also drain the x loads issued after last publish. ----
        if (w == 0) {
            const unsigned long long* fp =
                reinterpret_cast<const unsigned long long*>(gflags + lane * 2);
            for (;;) {
                unsigned long long v = __hip_atomic_load(fp, __ATOMIC_RELAXED,
                                                         __HIP_MEMORY_SCOPE_AGENT);
                int f0 = (int)(v & 0xffffffffu);
                int f1 = (int)(v >> 32);
                if (__all(f0 >= t && f1 >= t)) break;
                __builtin_amdgcn_s_sleep(1);
            }
            // no fence: h loads below are sc1 (coherent past L2)
        }
        __syncthreads();   // drains vmcnt for all waves

        // ---- issue h sc1 burst: 16 x dwordx4 (bf16-only, 8 elems each) ----
        const unsigned short* hb0 = hpack + (size_t)(t & 1) * (NB * NH)
                                  + (size_t)(g * 32 + lm) * NH + w * 256 + lq * 8;
        const unsigned short* hb1 = hb0 + (size_t)16 * NH;
        i32x4 q[8][2];   // [ks][mt]
        GLD2(0, 0);   GLD2(1, 64);  GLD2(2, 128); GLD2(3, 192);
        GLD2(4, 256); GLD2(5, 320); GLD2(6, 384); GLD2(7, 448);

        // ---- x-phase in the h-load shadow: hi/lo convert + 48 MFMAs ----
        f32x4 acc[2][2];
        #pragma unroll
        for (int mt = 0; mt < 2; ++mt)
            #pragma unroll
            for (int nt = 0; nt < 2; ++nt) {
                acc[mt][nt][0] = 0.f; acc[mt][nt][1] = 0.f;
                acc[mt][nt][2] = 0.f; acc[mt][nt][3] = 0.f;
            }
        #pragma unroll
        for (int ks = 0; ks < 4; ++ks) {
            bf16x8 axh[2], axl[2];
            #pragma unroll
            for (int mt = 0; mt < 2; ++mt) {
                f32x4 vlo = xr[mt][ks][0], vhi = xr[mt][ks][1];
                #pragma unroll
                for (int j = 0; j < 4; ++j) {
                    unsigned short h0 = f2bf(vlo[j]);
                    axh[mt][j]     = (short)h0;
                    axl[mt][j]     = (short)f2bf(vlo[j] - bf2f(h0));
                    unsigned short h1 = f2bf(vhi[j]);
                    axh[mt][4 + j] = (short)h1;
                    axl[mt][4 + j] = (short)f2bf(vhi[j] - bf2f(h1));
                }
            }
            #pragma unroll
            for (int mt = 0; mt < 2; ++mt)
                #pragma unroll
                for (int nt = 0; nt < 2; ++nt) {
                    acc[mt][nt] = __builtin_amdgcn_mfma_f32_16x16x32_bf16(axh[mt], wxh[nt][ks], acc[mt][nt], 0, 0, 0);
                    acc[mt][nt] = __builtin_amdgcn_mfma_f32_16x16x32_bf16(axh[mt], wxl[nt][ks], acc[mt][nt], 0, 0, 0);
                    acc[mt][nt] = __builtin_amdgcn_mfma_f32_16x16x32_bf16(axl[mt], wxh[nt][ks], acc[mt][nt], 0, 0, 0);
                }
        }

        // ---- h-phase: chunked waits (16 outstanding), 2-term MFMAs ----
        HKS(14, 0) HKS(12, 1) HKS(10, 2) HKS(8, 3)
        HKS(6, 4)  HKS(4, 5)  HKS(2, 6)  HKS(0, 7)

        // ---- cross-wave K-reduction via LDS (D: row = lq*4+r, col = lm) ----
        #pragma unroll
        for (int mt = 0; mt < 2; ++mt)
            #pragma unroll
            for (int nt = 0; nt < 2; ++nt)
                #pragma unroll
                for (int r = 0; r < 4; ++r)
                    zl[w][mt][nt][lq * 4 + r][lm] = acc[mt][nt][r];
        __syncthreads();

        // ---- epilogue: threads 0..127 (waves 0,1) do 2 cells each ----
        if (tid < 128) {
            float hv[2];
            #pragma unroll
            for (int j = 0; j < 2; ++j) {
                float zg[4];
                #pragma unroll
                for (int gt = 0; gt < 4; ++gt) {
                    const int nt = gt >> 1;
                    const int n  = (gt & 1) * 8 + prc * 2 + j;
                    zg[gt] = zl[0][emt][nt][emr][n] + zl[1][emt][nt][emr][n]
                           + zl[2][emt][nt][emr][n] + zl[3][emt][nt][emr][n]
                           + bgate[j][gt];
                }
                // Keras gate order: i, f, g, o
                float ig = sigm(zg[0]);
                float fg = sigm(zg[1]);
                float gg = tanh_f(zg[2]);
                float og = sigm(zg[3]);
                c2[j] = fg * c2[j] + ig * gg;
                hv[j] = og * tanh_f(c2[j]);
            }
            // pack two adjacent cols into one u32 (little-endian: low = colp)
            unsigned pk = (unsigned)f2bf(hv[0]) | ((unsigned)f2bf(hv[1]) << 16);
            const size_t po = (size_t)((t + 1) & 1) * (NB * NH / 2)
                            + (size_t)gbatch * (NH / 2) + bi * 4 + prc;
            __hip_atomic_store(hpk32 + po, pk, __ATOMIC_RELAXED, __HIP_MEMORY_SCOPE_AGENT);
            if (t == NT - 1) {
                hF32[(size_t)gbatch * NH + colp]     = hv[0];
                hF32[(size_t)gbatch * NH + colp + 1] = hv[1];
            }
        }

        // ---- publish: syncthreads drains vmcnt (h store at coherence point),
        // then relaxed flag store — no fences ----
        __syncthreads();
        if (tid == 0)
            __hip_atomic_store(myflag, t + 1, __ATOMIC_RELAXED, __HIP_MEMORY_SCOPE_AGENT);

        // ---- x-prefetch for t+1 AFTER publish (r8 placement: flies during
        // the spin window; drained by the next poll/barrier) ----
        if (t + 1 < NT) {
            #pragma unroll
            for (int mt = 0; mt < 2; ++mt) {
                const float* xs = x + ((size_t)(g * 32 + mt * 16 + lm) * NT + (t + 1)) * NS
                                    + w * 128 + lq * 8;
                #pragma unroll
                for (int ks = 0; ks < 4; ++ks) {
                    const f32x4* p = reinterpret_cast<const f32x4*>(xs + ks * 32);
                    xr[mt][ks][0] = p[0];
                    xr[mt][ks][1] = p[1];
                }
            }
        }
    }
}

// hid = relu(hF32 @ Wd1 + bd1)   [64,1024]x[1024,512]
__global__ void head1(const float* __restrict__ hF32, const float* __restrict__ Wd1,
                      const float* __restrict__ bd1, float* __restrict__ hid)
{
    int b = blockIdx.x >> 1;
    int n = (blockIdx.x & 1) * 256 + threadIdx.x;
    const float* hrow = hF32 + (size_t)b * NH;
    float acc = bd1[n];
    #pragma unroll 4
    for (int k = 0; k < NH; ++k)
        acc += hrow[k] * Wd1[(size_t)k * NHD + n];
    hid[(size_t)b * NHD + n] = fmaxf(acc, 0.0f);
}

// out = [hid | actions | horizon] @ Wd2 + bd2   K = 512 + 64 + 1 = 577
__global__ void head2(const float* __restrict__ hid, const float* __restrict__ act,
                      const float* __restrict__ hor, const float* __restrict__ Wd2,
                      const float* __restrict__ bd2, float* __restrict__ out)
{
    int b = blockIdx.x;
    int n = threadIdx.x;
    float acc = bd2[n];
    const float* hrow = hid + (size_t)b * NHD;
    #pragma unroll 4
    for (int k = 0; k < NHD; ++k) acc += hrow[k] * Wd2[(size_t)k * NO + n];
    const float* arow = act + (size_t)b * NA;
    #pragma unroll
    for (int k = 0; k < NA; ++k) acc += arow[k] * Wd2[(size_t)(NHD + k) * NO + n];
    acc += hor[b] * Wd2[(size_t)576 * NO + n];
    out[(size_t)b * NO + n] = acc;
}

extern "C" void kernel_launch(void* const* d_in, const int* in_sizes, int n_in,
                              void* d_out, int out_size, void* d_ws, size_t ws_size,
                              hipStream_t stream)
{
    (void)in_sizes; (void)n_in; (void)out_size; (void)ws_size;
    const float* x    = (const float*)d_in[0];
    const float* act  = (const float*)d_in[1];
    const float* hor  = (const float*)d_in[2];
    const float* Wx   = (const float*)d_in[3];
    const float* Wh   = (const float*)d_in[4];
    const float* bias = (const float*)d_in[5];
    const float* Wd1  = (const float*)d_in[6];
    const float* bd1  = (const float*)d_in[7];
    const float* Wd2  = (const float*)d_in[8];
    const float* bd2  = (const float*)d_in[9];
    float* out = (float*)d_out;

    char* wsb = (char*)d_ws;
    unsigned short* hpk = (unsigned short*)(wsb + WS_HPK);
    float* hF32 = (float*)(wsb + WS_HF32);
    float* hid  = (float*)(wsb + WS_HID);
    int*   flg  = (int*)(wsb + WS_FLG);

    prologue<<<256, 256, 0, stream>>>((unsigned int*)(wsb + WS_HPK),
                                      (unsigned int*)(wsb + WS_FLG));

    // Plain launch (NOT cooperative — see r2 post-mortem). 256 blocks == 256 CUs.
    lstm_persist<<<dim3(256), dim3(256), 0, stream>>>(x, Wx, Wh, bias,
                                                      hpk, hF32, flg);

    head1<<<128, 256, 0, stream>>>(hF32, Wd1, bd1, hid);
    head2<<<64, 64, 0, stream>>>(hid, act, hor, Wd2, bd2, out);
}